// Round 1
// baseline (713.544 us; speedup 1.0000x reference)
//
#include <hip/hip_runtime.h>
#include <hip/hip_bf16.h>

#define BB 8
#define CC 64
#define HH 64
#define WW 64
#define KK 4096
#define HWSZ (HH*WW)          // 4096
#define NQ (BB*HWSZ)          // 32768
#define NELEM (NQ*CC)         // 2097152

// ---------------- codebook norms ----------------
__global__ void k_cn(const float* __restrict__ cb, float* __restrict__ cn) {
    int k = blockIdx.x * 256 + threadIdx.x;
    const float4* r = (const float4*)(cb + (size_t)k * 64);
    float s = 0.f;
#pragma unroll
    for (int i = 0; i < 16; i++) {
        float4 v = r[i];
        s += v.x * v.x + v.y * v.y + v.z * v.z + v.w * v.w;
    }
    cn[k] = s;
}

// ---------------- conv_in: NCHW [8,3,64,64] -> feat NHWC [8,64,64,64] ----------------
__global__ void k_conv_in(const float* __restrict__ x, const float* __restrict__ w,
                          const float* __restrict__ bias, float* __restrict__ feat) {
    int tid = blockIdx.x * 256 + threadIdx.x;   // (b,h,w,co), co fastest
    int co = tid & 63;
    int sp = tid >> 6;                          // b*4096 + h*64 + w
    int wq = sp & 63;
    int h  = (sp >> 6) & 63;
    int b  = sp >> 12;
    float acc = bias[co];
#pragma unroll
    for (int ci = 0; ci < 3; ci++) {
#pragma unroll
        for (int kh = 0; kh < 3; kh++) {
            int hh = h + kh - 1;
            if (hh < 0 || hh >= 64) continue;
#pragma unroll
            for (int kw = 0; kw < 3; kw++) {
                int ww = wq + kw - 1;
                if (ww < 0 || ww >= 64) continue;
                float xv = x[((b * 3 + ci) << 12) + (hh << 6) + ww];
                float wv = w[((co * 3 + ci) * 3 + kh) * 3 + kw];
                acc += xv * wv;
            }
        }
    }
    feat[tid] = acc;
}

// ---------------- argmin + gather + quant write + ssd ----------------
// block: 512 threads = 8 waves. Each wave handles the SAME 64 queries (one per lane)
// with a wave-uniform chunk of 512 codes -> codebook loads scalarize.
__global__ __launch_bounds__(512, 4) void k_argmin(
    const float* __restrict__ feat, const float* __restrict__ cb,
    const float* __restrict__ cn, float* __restrict__ quant,
    float* __restrict__ ssd_accum) {
    int lane = threadIdx.x & 63;
    int wv   = threadIdx.x >> 6;                 // 0..7
    int q    = (blockIdx.x << 6) + lane;         // query id

    // load query vector into registers (static-indexed after unroll)
    float qf[64];
    const float4* qp = (const float4*)(feat + (size_t)q * 64);
#pragma unroll
    for (int i = 0; i < 16; i++) {
        float4 v = qp[i];
        qf[4 * i + 0] = v.x; qf[4 * i + 1] = v.y;
        qf[4 * i + 2] = v.z; qf[4 * i + 3] = v.w;
    }

    int chunk = __builtin_amdgcn_readfirstlane(wv);   // wave-uniform
    int k0 = chunk << 9;                              // 512 codes per wave
    float best = 3.4e38f;
    int   bi   = 0;
    for (int j = 0; j < 512; j++) {
        int k = k0 + j;
        const float4* cp = (const float4*)(cb + ((size_t)k << 6));
        float d0 = 0.f, d1 = 0.f, d2 = 0.f, d3 = 0.f;
#pragma unroll
        for (int i = 0; i < 16; i += 4) {
            float4 c0 = cp[i], c1 = cp[i + 1], c2 = cp[i + 2], c3 = cp[i + 3];
            d0 += qf[4*i+ 0]*c0.x + qf[4*i+ 1]*c0.y + qf[4*i+ 2]*c0.z + qf[4*i+ 3]*c0.w;
            d1 += qf[4*i+ 4]*c1.x + qf[4*i+ 5]*c1.y + qf[4*i+ 6]*c1.z + qf[4*i+ 7]*c1.w;
            d2 += qf[4*i+ 8]*c2.x + qf[4*i+ 9]*c2.y + qf[4*i+10]*c2.z + qf[4*i+11]*c2.w;
            d3 += qf[4*i+12]*c3.x + qf[4*i+13]*c3.y + qf[4*i+14]*c3.z + qf[4*i+15]*c3.w;
        }
        float dot = (d0 + d1) + (d2 + d3);
        float score = cn[k] - 2.f * dot;     // ||q||^2 dropped (argmin-invariant)
        if (score < best) { best = score; bi = k; }
    }

    __shared__ float sb[8][64];
    __shared__ int   si[8][64];
    sb[wv][lane] = best;
    si[wv][lane] = bi;
    __syncthreads();

    if (wv == 0) {
#pragma unroll
        for (int o = 1; o < 8; o++) {
            float b2 = sb[o][lane];
            int   i2 = si[o][lane];
            if (b2 < best) { best = b2; bi = i2; }   // strict < keeps lowest k on ties
        }
        // gather codebook row, write quant (NCHW), accumulate ssd
        int bq = q >> 12;
        int hw = q & 4095;
        const float* crow = cb + ((size_t)bi << 6);
        float* qout = quant + ((size_t)bq << 18) + hw;  // + c*4096 per channel
        float ssd = 0.f;
#pragma unroll
        for (int c = 0; c < 64; c++) {
            float cvv = crow[c];
            float dd = cvv - qf[c];
            ssd += dd * dd;
            qout[(size_t)c << 12] = cvv;
        }
#pragma unroll
        for (int off = 32; off; off >>= 1) ssd += __shfl_down(ssd, off);
        if (lane == 0) atomicAdd(ssd_accum, ssd);
    }
}

// ---------------- group-norm stats ----------------
__global__ void k_gn_stats(const float* __restrict__ quant,
                           float* __restrict__ meanv, float* __restrict__ rstdv) {
    int grp = blockIdx.x;                       // b*8+g, contiguous 32768 floats
    const float4* base = (const float4*)(quant + (size_t)grp * 32768);
    float s = 0.f, s2 = 0.f;
    for (int i = threadIdx.x; i < 8192; i += 256) {
        float4 v = base[i];
        s  += v.x + v.y + v.z + v.w;
        s2 += v.x * v.x + v.y * v.y + v.z * v.z + v.w * v.w;
    }
    __shared__ float ls[256], ls2[256];
    ls[threadIdx.x] = s; ls2[threadIdx.x] = s2;
    __syncthreads();
    for (int off = 128; off; off >>= 1) {
        if (threadIdx.x < off) {
            ls[threadIdx.x]  += ls[threadIdx.x + off];
            ls2[threadIdx.x] += ls2[threadIdx.x + off];
        }
        __syncthreads();
    }
    if (threadIdx.x == 0) {
        float m = ls[0] / 32768.f;
        float var = ls2[0] / 32768.f - m * m;
        meanv[grp] = m;
        rstdv[grp] = rsqrtf(var + 1e-5f);
    }
}

// ---------------- group-norm apply + SiLU ----------------
__global__ void k_norm_silu(const float* __restrict__ quant,
                            const float* __restrict__ meanv, const float* __restrict__ rstdv,
                            const float* __restrict__ scale, const float* __restrict__ bias,
                            float* __restrict__ normed) {
    int t = blockIdx.x * 256 + threadIdx.x;     // float4 index
    int c = (t >> 10) & 63;
    int b = t >> 16;
    int grp = b * 8 + (c >> 3);
    float m = meanv[grp], r = rstdv[grp];
    float sc = scale[c] * r;
    float bi = bias[c] - m * sc;
    float4 v = ((const float4*)quant)[t];
    float4 o;
    float y;
    y = v.x * sc + bi; o.x = y / (1.f + expf(-y));
    y = v.y * sc + bi; o.y = y / (1.f + expf(-y));
    y = v.z * sc + bi; o.z = y / (1.f + expf(-y));
    y = v.w * sc + bi; o.w = y / (1.f + expf(-y));
    ((float4*)normed)[t] = o;
}

// ---------------- conv_out: NCHW [8,64,64,64] -> [8,3,64,64] ----------------
__global__ void k_conv_out(const float* __restrict__ normed, const float* __restrict__ w,
                           const float* __restrict__ bias, float* __restrict__ out) {
    int tid = blockIdx.x * 256 + threadIdx.x;   // b*12288 + co*4096 + h*64 + w
    int wq = tid & 63;
    int h  = (tid >> 6) & 63;
    int co = (tid >> 12) % 3;
    int b  = tid / 12288;
    float acc = bias[co];
    for (int ci = 0; ci < 64; ci++) {
#pragma unroll
        for (int kh = 0; kh < 3; kh++) {
            int hh = h + kh - 1;
            if (hh < 0 || hh >= 64) continue;
#pragma unroll
            for (int kw = 0; kw < 3; kw++) {
                int ww = wq + kw - 1;
                if (ww < 0 || ww >= 64) continue;
                acc += normed[(((b << 6) + ci) << 12) + (hh << 6) + ww]
                     * w[((co * 64 + ci) * 3 + kh) * 3 + kw];
            }
        }
    }
    out[tid] = acc;
}

// ---------------- losses ----------------
__global__ void k_loss(const float* __restrict__ ssd, float* __restrict__ losses) {
    float mean = ssd[0] / 2097152.f;
    losses[0] = mean;            // commitment_loss (CODEBOOK_WEIGHT = 1.0)
    losses[1] = 0.25f * mean;    // code_book_loss  (BETA = 0.25)
}

extern "C" void kernel_launch(void* const* d_in, const int* in_sizes, int n_in,
                              void* d_out, int out_size, void* d_ws, size_t ws_size,
                              hipStream_t stream) {
    const float* x   = (const float*)d_in[0];
    const float* ciw = (const float*)d_in[1];
    const float* cib = (const float*)d_in[2];
    const float* cb  = (const float*)d_in[3];
    const float* gsc = (const float*)d_in[4];
    const float* gbi = (const float*)d_in[5];
    const float* dw  = (const float*)d_in[6];
    const float* db  = (const float*)d_in[7];

    float* out = (float*)d_out;
    float* ws  = (float*)d_ws;

    float* ssd   = ws;            // [0]
    float* meanv = ws + 64;       // 64
    float* rstdv = ws + 128;      // 64
    float* cn    = ws + 256;      // 4096
    float* feat  = ws + 8192;     // NELEM floats (NHWC); reused as `normed` (NCHW)

    float* recon  = out;                    // 98304
    float* quant  = out + 98304;            // NELEM
    float* losses = out + 98304 + NELEM;    // 2

    hipMemsetAsync(ssd, 0, 64, stream);
    k_cn       <<<KK / 256, 256, 0, stream>>>(cb, cn);
    k_conv_in  <<<NELEM / 256, 256, 0, stream>>>(x, ciw, cib, feat);
    k_argmin   <<<NQ / 64, 512, 0, stream>>>(feat, cb, cn, quant, ssd);
    k_gn_stats <<<64, 256, 0, stream>>>(quant, meanv, rstdv);
    k_norm_silu<<<NELEM / 4 / 256, 256, 0, stream>>>(quant, meanv, rstdv, gsc, gbi, feat);
    k_conv_out <<<(BB * 3 * HWSZ) / 256, 256, 0, stream>>>(feat, dw, db, recon);
    k_loss     <<<1, 1, 0, stream>>>(ssd, losses);
}

// Round 2
// 449.578 us; speedup vs baseline: 1.5871x; 1.5871x over previous
//
#include <hip/hip_runtime.h>
#include <hip/hip_bf16.h>

typedef __attribute__((ext_vector_type(8))) short short8;
typedef __attribute__((ext_vector_type(4))) float f32x4;

#define BB 8
#define KK 4096
#define HWSZ 4096
#define NQ 32768
#define NELEM 2097152
#define TAU 0.02f
#define RESCUE_CAP 8192

__device__ __forceinline__ unsigned short f2bf(float f) {
    unsigned u = __float_as_uint(f);
    u = (u + 0x7FFFu + ((u >> 16) & 1u)) >> 16;
    return (unsigned short)u;
}
__device__ __forceinline__ float bf2f(unsigned short h) {
    return __uint_as_float(((unsigned)h) << 16);
}

// ---------------- codebook prep: norms + bf16 hi/lo split ----------------
__global__ void k_prep(const float* __restrict__ cb, float* __restrict__ cn,
                       unsigned short* __restrict__ cbh, unsigned short* __restrict__ cbl) {
    int k = blockIdx.x * 256 + threadIdx.x;
    const float* r = cb + (size_t)k * 64;
    float s = 0.f;
    short8 hv[8], lv[8];
#pragma unroll
    for (int j = 0; j < 8; j++) {
#pragma unroll
        for (int e = 0; e < 8; e++) {
            float v = r[j * 8 + e];
            s += v * v;
            unsigned short h = f2bf(v);
            hv[j][e] = (short)h;
            lv[j][e] = (short)f2bf(v - bf2f(h));
        }
    }
    cn[k] = s;
    short8* oh = (short8*)(cbh + (size_t)k * 64);
    short8* ol = (short8*)(cbl + (size_t)k * 64);
#pragma unroll
    for (int j = 0; j < 8; j++) { oh[j] = hv[j]; ol[j] = lv[j]; }
}

// ---------------- conv_in: NCHW [8,3,64,64] -> feat hi/lo bf16 NHWC ----------------
__global__ void k_conv_in(const float* __restrict__ x, const float* __restrict__ w,
                          const float* __restrict__ bias,
                          unsigned short* __restrict__ fh, unsigned short* __restrict__ fl) {
    int tid = blockIdx.x * 256 + threadIdx.x;   // (b,h,w,co), co fastest
    int co = tid & 63;
    int sp = tid >> 6;
    int wq = sp & 63;
    int h  = (sp >> 6) & 63;
    int b  = sp >> 12;
    float acc = bias[co];
#pragma unroll
    for (int ci = 0; ci < 3; ci++) {
#pragma unroll
        for (int kh = 0; kh < 3; kh++) {
            int hh = h + kh - 1;
            if (hh < 0 || hh >= 64) continue;
#pragma unroll
            for (int kw = 0; kw < 3; kw++) {
                int ww = wq + kw - 1;
                if (ww < 0 || ww >= 64) continue;
                acc += x[((b * 3 + ci) << 12) + (hh << 6) + ww]
                     * w[((co * 3 + ci) * 3 + kh) * 3 + kw];
            }
        }
    }
    unsigned short hbits = f2bf(acc);
    fh[tid] = hbits;
    fl[tid] = f2bf(acc - bf2f(hbits));
}

#define AS1 __attribute__((address_space(1)))
#define AS3 __attribute__((address_space(3)))

// ---------------- MFMA argmin + gather + quant + ssd ----------------
// 512 blocks x 256 thr (4 waves). Block owns 64 queries; wave w owns code
// tile w within each 64-code chunk. Codebook chunk staged to LDS dbuf with
// XOR-swizzled (j^row&7) 16B slots via pre-swizzled global_load_lds source.
__global__ __launch_bounds__(256, 2) void k_argmin(
    const unsigned short* __restrict__ fh, const unsigned short* __restrict__ fl,
    const unsigned short* __restrict__ cbh, const unsigned short* __restrict__ cbl,
    const float* __restrict__ cn, const float* __restrict__ cb,
    float* __restrict__ quant, float* __restrict__ ssd,
    unsigned int* __restrict__ rcnt, int* __restrict__ rlist) {

    __shared__ char smem[32768];          // 2 bufs x (hi 8KB | lo 8KB)
    __shared__ float mb1[4][64];
    __shared__ float mb2[4][64];
    __shared__ int   mi1[4][64];
    __shared__ int   fi[64];

    const int tid = threadIdx.x;
    const int L   = tid & 63;
    const int w   = tid >> 6;             // wave 0..3
    const int col = L & 15;
    const int g   = L >> 4;
    const int blk = blockIdx.x;

    // ---- A fragments: 4 m-tiles x 2 k-halves, hi+lo ----
    short8 qh[4][2], ql[4][2];
#pragma unroll
    for (int mt = 0; mt < 4; mt++) {
        int qrow = blk * 64 + mt * 16 + col;
        const short8* ph = (const short8*)(fh + (size_t)qrow * 64);
        const short8* pl = (const short8*)(fl + (size_t)qrow * 64);
#pragma unroll
        for (int kh = 0; kh < 2; kh++) {
            qh[mt][kh] = ph[kh * 4 + g];
            ql[mt][kh] = pl[kh * 4 + g];
        }
    }

    // per-lane swizzled LDS read offsets (B frags), row = w*16+col
    const int row_in = w * 16 + col;
    const int a0 = row_in * 128 + ((g ^ (L & 7)) * 16);
    const int a1 = row_in * 128 + (((4 + g) ^ (L & 7)) * 16);

    // staging: slot s = tid (+256 per round); row=s>>3, j=(s&7)^(row&7)
    const int srow = tid >> 3;
    const int soff = srow * 128 + (((tid & 7) ^ (srow & 7)) * 16);
    const int dbase = w * 1024;           // wave-uniform LDS dest base

    float vb1[4][4], vb2[4][4];
    int   vi1[4][4];
#pragma unroll
    for (int mt = 0; mt < 4; mt++)
#pragma unroll
        for (int e = 0; e < 4; e++) { vb1[mt][e] = 3.4e38f; vb2[mt][e] = 3.4e38f; vi1[mt][e] = 0; }

    const char* ghb = (const char*)cbh;
    const char* glb = (const char*)cbl;

    auto stage = [&](int c, int boff) {
        const char* gh = ghb + c * 8192 + soff;
        const char* gl = glb + c * 8192 + soff;
        char* l0 = smem + boff + dbase;
        __builtin_amdgcn_global_load_lds((const AS1 void*)gh,          (AS3 void*)l0,           16, 0, 0);
        __builtin_amdgcn_global_load_lds((const AS1 void*)(gh + 4096), (AS3 void*)(l0 + 4096),  16, 0, 0);
        __builtin_amdgcn_global_load_lds((const AS1 void*)gl,          (AS3 void*)(l0 + 8192),  16, 0, 0);
        __builtin_amdgcn_global_load_lds((const AS1 void*)(gl + 4096), (AS3 void*)(l0 + 12288), 16, 0, 0);
    };

    stage(0, 0);
    __syncthreads();

    int bufoff = 0;
#pragma unroll 1
    for (int c = 0; c < 64; c++) {
        if (c + 1 < 64) stage(c + 1, bufoff ^ 16384);

        const int kbase = c * 64 + w * 16;
        const int kv = kbase + col;
        const float cnk = cn[kv];
        const char* bbase = smem + bufoff;
        const short8* p0 = (const short8*)(bbase + a0);
        const short8* p1 = (const short8*)(bbase + a1);
        short8 bh0 = p0[0];
        short8 bh1 = p1[0];
        short8 bl0 = p0[512];   // +8192 bytes
        short8 bl1 = p1[512];
#pragma unroll
        for (int mt = 0; mt < 4; mt++) {
            f32x4 acc = {0.f, 0.f, 0.f, 0.f};
            acc = __builtin_amdgcn_mfma_f32_16x16x32_bf16(qh[mt][0], bh0, acc, 0, 0, 0);
            acc = __builtin_amdgcn_mfma_f32_16x16x32_bf16(qh[mt][1], bh1, acc, 0, 0, 0);
            acc = __builtin_amdgcn_mfma_f32_16x16x32_bf16(qh[mt][0], bl0, acc, 0, 0, 0);
            acc = __builtin_amdgcn_mfma_f32_16x16x32_bf16(qh[mt][1], bl1, acc, 0, 0, 0);
            acc = __builtin_amdgcn_mfma_f32_16x16x32_bf16(ql[mt][0], bh0, acc, 0, 0, 0);
            acc = __builtin_amdgcn_mfma_f32_16x16x32_bf16(ql[mt][1], bh1, acc, 0, 0, 0);
#pragma unroll
            for (int e = 0; e < 4; e++) {
                float s = fmaf(acc[e], -2.f, cnk);
                vb2[mt][e] = __builtin_amdgcn_fmed3f(s, vb1[mt][e], vb2[mt][e]);
                bool take = s < vb1[mt][e];
                vi1[mt][e] = take ? kv : vi1[mt][e];
                vb1[mt][e] = take ? s : vb1[mt][e];
            }
        }
        __syncthreads();
        bufoff ^= 16384;
    }

    // ---- cross-lane (16-group) top-2 merge, then cross-wave via LDS ----
#pragma unroll
    for (int mt = 0; mt < 4; mt++)
#pragma unroll
    for (int e = 0; e < 4; e++) {
        float b1 = vb1[mt][e], b2 = vb2[mt][e];
        int i1 = vi1[mt][e];
#pragma unroll
        for (int m = 1; m < 16; m <<= 1) {
            float ob1 = __shfl_xor(b1, m, 64);
            float ob2 = __shfl_xor(b2, m, 64);
            int   oi1 = __shfl_xor(i1, m, 64);
            float hi = fmaxf(b1, ob1);
            b2 = fminf(fminf(b2, ob2), hi);
            bool take = (ob1 < b1) || ((ob1 == b1) && (oi1 < i1));
            if (take) { b1 = ob1; i1 = oi1; }
        }
        if (col == 0) {
            int qloc = mt * 16 + g * 4 + e;
            mb1[w][qloc] = b1; mb2[w][qloc] = b2; mi1[w][qloc] = i1;
        }
    }
    __syncthreads();

    if (tid < 64) {
        float b1 = mb1[0][tid], b2 = mb2[0][tid];
        int i1 = mi1[0][tid];
#pragma unroll
        for (int w2 = 1; w2 < 4; w2++) {
            float ob1 = mb1[w2][tid], ob2 = mb2[w2][tid];
            int   oi1 = mi1[w2][tid];
            float hi = fmaxf(b1, ob1);
            b2 = fminf(fminf(b2, ob2), hi);
            bool take = (ob1 < b1) || ((ob1 == b1) && (oi1 < i1));
            if (take) { b1 = ob1; i1 = oi1; }
        }
        fi[tid] = i1;
        if (b2 - b1 < TAU) {
            unsigned pos = atomicAdd(rcnt, 1u);
            if (pos < RESCUE_CAP) {
                rlist[2 * pos] = blk * 64 + tid;
                rlist[2 * pos + 1] = i1;
            }
        }
    }
    __syncthreads();

    // ---- gather + quant write (NCHW) + ssd ----
    {
        int qloc = tid >> 2, part = tid & 3;
        int idx = fi[qloc];
        int q = blk * 64 + qloc;
        int b = q >> 12, hw = q & 4095;
        const float* crow = cb + (size_t)idx * 64 + part * 16;
        const short8* phh = (const short8*)(fh + (size_t)q * 64) + part * 2;
        const short8* pll = (const short8*)(fl + (size_t)q * 64) + part * 2;
        short8 h0 = phh[0], h1 = phh[1], l0 = pll[0], l1 = pll[1];
        float* qout = quant + ((size_t)b << 18) + ((size_t)(part * 16) << 12) + hw;
        float ps = 0.f;
#pragma unroll
        for (int cc = 0; cc < 16; cc++) {
            float fv = bf2f((unsigned short)(cc < 8 ? h0[cc] : h1[cc - 8]))
                     + bf2f((unsigned short)(cc < 8 ? l0[cc] : l1[cc - 8]));
            float cv = crow[cc];
            float d = cv - fv;
            ps += d * d;
            qout[(size_t)cc << 12] = cv;
        }
#pragma unroll
        for (int off = 32; off; off >>= 1) ps += __shfl_down(ps, off, 64);
        if (L == 0) atomicAdd(ssd, ps);
    }
}

// ---------------- exact fp32 rescue for near-tie queries ----------------
__global__ void k_rescue(const int* __restrict__ rlist, const unsigned int* __restrict__ rcnt,
                         const unsigned short* __restrict__ fh, const unsigned short* __restrict__ fl,
                         const float* __restrict__ cb, const float* __restrict__ cn,
                         float* __restrict__ quant, float* __restrict__ ssd) {
    __shared__ float fq[64];
    __shared__ float sb[256];
    __shared__ int   si[256];
    __shared__ int   s_new;
    int tid = threadIdx.x;
    unsigned cnt = *rcnt;
    int n = (int)(cnt > RESCUE_CAP ? RESCUE_CAP : cnt);
    for (int r = blockIdx.x; r < n; r += gridDim.x) {
        int q = rlist[2 * r], old_i = rlist[2 * r + 1];
        if (tid < 64) fq[tid] = bf2f(fh[(size_t)q * 64 + tid]) + bf2f(fl[(size_t)q * 64 + tid]);
        __syncthreads();
        float best = 3.4e38f; int bi = 0;
        for (int kk = 0; kk < 16; kk++) {
            int k = kk * 256 + tid;
            const float4* cp = (const float4*)(cb + (size_t)k * 64);
            float d0 = 0.f, d1 = 0.f, d2 = 0.f, d3 = 0.f;
#pragma unroll
            for (int i = 0; i < 16; i += 4) {
                float4 c0 = cp[i], c1 = cp[i+1], c2 = cp[i+2], c3 = cp[i+3];
                d0 += fq[4*i+ 0]*c0.x + fq[4*i+ 1]*c0.y + fq[4*i+ 2]*c0.z + fq[4*i+ 3]*c0.w;
                d1 += fq[4*i+ 4]*c1.x + fq[4*i+ 5]*c1.y + fq[4*i+ 6]*c1.z + fq[4*i+ 7]*c1.w;
                d2 += fq[4*i+ 8]*c2.x + fq[4*i+ 9]*c2.y + fq[4*i+10]*c2.z + fq[4*i+11]*c2.w;
                d3 += fq[4*i+12]*c3.x + fq[4*i+13]*c3.y + fq[4*i+14]*c3.z + fq[4*i+15]*c3.w;
            }
            float s = cn[k] - 2.f * ((d0 + d1) + (d2 + d3));
            if (s < best) { best = s; bi = k; }
        }
        sb[tid] = best; si[tid] = bi;
        __syncthreads();
        for (int off = 128; off; off >>= 1) {
            if (tid < off) {
                float ob = sb[tid + off]; int oi = si[tid + off];
                if (ob < sb[tid] || (ob == sb[tid] && oi < si[tid])) { sb[tid] = ob; si[tid] = oi; }
            }
            __syncthreads();
        }
        if (tid == 0) s_new = si[0];
        __syncthreads();
        int new_i = s_new;
        if (new_i != old_i && tid < 64) {
            float fv = fq[tid];
            float co = cb[(size_t)old_i * 64 + tid];
            float cw = cb[(size_t)new_i * 64 + tid];
            int b = q >> 12, hw = q & 4095;
            quant[((size_t)b << 18) + ((size_t)tid << 12) + hw] = cw;
            float dd = (cw - fv) * (cw - fv) - (co - fv) * (co - fv);
#pragma unroll
            for (int off = 32; off; off >>= 1) dd += __shfl_down(dd, off, 64);
            if (tid == 0) atomicAdd(ssd, dd);
        }
        __syncthreads();
    }
}

// ---------------- group-norm partial stats (atomic accumulate) ----------------
__global__ void k_gn_stats(const float* __restrict__ quant,
                           float* __restrict__ gsum, float* __restrict__ gsq) {
    int grp = blockIdx.x >> 3, slice = blockIdx.x & 7;
    const float4* base = (const float4*)(quant + (size_t)grp * 32768 + slice * 4096);
    float s = 0.f, s2 = 0.f;
#pragma unroll
    for (int i = 0; i < 4; i++) {
        float4 v = base[threadIdx.x + i * 256];
        s  += v.x + v.y + v.z + v.w;
        s2 += v.x * v.x + v.y * v.y + v.z * v.z + v.w * v.w;
    }
#pragma unroll
    for (int off = 32; off; off >>= 1) {
        s  += __shfl_down(s, off, 64);
        s2 += __shfl_down(s2, off, 64);
    }
    if ((threadIdx.x & 63) == 0) {
        atomicAdd(&gsum[grp], s);
        atomicAdd(&gsq[grp], s2);
    }
}

// ---------------- group-norm apply + SiLU ----------------
__global__ void k_norm_silu(const float* __restrict__ quant,
                            const float* __restrict__ gsum, const float* __restrict__ gsq,
                            const float* __restrict__ scale, const float* __restrict__ bias,
                            float* __restrict__ normed) {
    int t = blockIdx.x * 256 + threadIdx.x;
    int c = (t >> 10) & 63;
    int b = t >> 16;
    int grp = b * 8 + (c >> 3);
    float m = gsum[grp] * (1.f / 32768.f);
    float var = gsq[grp] * (1.f / 32768.f) - m * m;
    float r = rsqrtf(var + 1e-5f);
    float sc = scale[c] * r;
    float bi = bias[c] - m * sc;
    float4 v = ((const float4*)quant)[t];
    float4 o;
    float y;
    y = v.x * sc + bi; o.x = y / (1.f + expf(-y));
    y = v.y * sc + bi; o.y = y / (1.f + expf(-y));
    y = v.z * sc + bi; o.z = y / (1.f + expf(-y));
    y = v.w * sc + bi; o.w = y / (1.f + expf(-y));
    ((float4*)normed)[t] = o;
}

// ---------------- conv_out: NCHW [8,64,64,64] -> [8,3,64,64] ----------------
__global__ void k_conv_out(const float* __restrict__ normed, const float* __restrict__ w,
                           const float* __restrict__ bias, float* __restrict__ out) {
    int tid = blockIdx.x * 256 + threadIdx.x;
    int wq = tid & 63;
    int h  = (tid >> 6) & 63;
    int co = (tid >> 12) % 3;
    int b  = tid / 12288;
    float acc = bias[co];
    for (int ci = 0; ci < 64; ci++) {
#pragma unroll
        for (int kh = 0; kh < 3; kh++) {
            int hh = h + kh - 1;
            if (hh < 0 || hh >= 64) continue;
#pragma unroll
            for (int kw = 0; kw < 3; kw++) {
                int ww = wq + kw - 1;
                if (ww < 0 || ww >= 64) continue;
                acc += normed[(((b << 6) + ci) << 12) + (hh << 6) + ww]
                     * w[((co * 64 + ci) * 3 + kh) * 3 + kw];
            }
        }
    }
    out[tid] = acc;
}

// ---------------- losses ----------------
__global__ void k_loss(const float* __restrict__ ssd, float* __restrict__ losses) {
    float mean = ssd[0] / 2097152.f;
    losses[0] = mean;
    losses[1] = 0.25f * mean;
}

extern "C" void kernel_launch(void* const* d_in, const int* in_sizes, int n_in,
                              void* d_out, int out_size, void* d_ws, size_t ws_size,
                              hipStream_t stream) {
    const float* x   = (const float*)d_in[0];
    const float* ciw = (const float*)d_in[1];
    const float* cib = (const float*)d_in[2];
    const float* cb  = (const float*)d_in[3];
    const float* gsc = (const float*)d_in[4];
    const float* gbi = (const float*)d_in[5];
    const float* dw  = (const float*)d_in[6];
    const float* db  = (const float*)d_in[7];

    float* out = (float*)d_out;
    char* wsb  = (char*)d_ws;

    float*          ssd   = (float*)wsb;                       // 4B
    unsigned int*   rcnt  = (unsigned int*)(wsb + 4);          // 4B
    float*          gsum  = (float*)(wsb + 64);                // 256B
    float*          gsq   = (float*)(wsb + 320);               // 256B
    float*          cn    = (float*)(wsb + 1024);              // 16KB
    int*            rlist = (int*)(wsb + 65536);               // 64KB
    unsigned short* cbh   = (unsigned short*)(wsb + 131072);   // 512KB
    unsigned short* cbl   = (unsigned short*)(wsb + 655360);   // 512KB
    unsigned short* fh    = (unsigned short*)(wsb + 1179648);  // 4MB
    unsigned short* fl    = fh + NELEM;                        // 4MB
    float*          normed = (float*)(wsb + 1179648);          // reuses fh/fl after argmin+rescue

    float* recon  = out;                    // 98304
    float* quant  = out + 98304;            // 2097152
    float* losses = out + 98304 + NELEM;    // 2

    hipMemsetAsync(wsb, 0, 1024, stream);
    k_prep     <<<16,   256, 0, stream>>>(cb, cn, cbh, cbl);
    k_conv_in  <<<8192, 256, 0, stream>>>(x, ciw, cib, fh, fl);
    k_argmin   <<<512,  256, 0, stream>>>(fh, fl, cbh, cbl, cn, cb, quant, ssd, rcnt, rlist);
    k_rescue   <<<256,  256, 0, stream>>>(rlist, rcnt, fh, fl, cb, cn, quant, ssd);
    k_gn_stats <<<512,  256, 0, stream>>>(quant, gsum, gsq);
    k_norm_silu<<<2048, 256, 0, stream>>>(quant, gsum, gsq, gsc, gbi, normed);
    k_conv_out <<<384,  256, 0, stream>>>(normed, dw, db, recon);
    k_loss     <<<1,    1,   0, stream>>>(ssd, losses);
}

// Round 3
// 302.875 us; speedup vs baseline: 2.3559x; 1.4844x over previous
//
#include <hip/hip_runtime.h>
#include <hip/hip_bf16.h>

typedef __attribute__((ext_vector_type(8))) short short8;
typedef __attribute__((ext_vector_type(4))) float f32x4;

#define KK 4096
#define NELEM 2097152
#define TAU 0.004f
#define RESCUE_CAP 8192

__device__ __forceinline__ unsigned short f2bf(float f) {
    unsigned u = __float_as_uint(f);
    u = (u + 0x7FFFu + ((u >> 16) & 1u)) >> 16;
    return (unsigned short)u;
}
__device__ __forceinline__ float bf2f(unsigned short h) {
    return __uint_as_float(((unsigned)h) << 16);
}

// ---------------- codebook prep: norms + bf16 hi/lo split ----------------
__global__ void k_prep(const float* __restrict__ cb, float* __restrict__ cn,
                       unsigned short* __restrict__ cbh, unsigned short* __restrict__ cbl) {
    int t = blockIdx.x * 256 + threadIdx.x;       // 16384 threads
    int row = t >> 2, part = t & 3;
    const float4* p = (const float4*)(cb + (size_t)row * 64 + part * 16);
    float s = 0.f;
    short8 hv[2], lv[2];
#pragma unroll
    for (int i = 0; i < 4; i++) {
        float4 v = p[i];
        float arr[4] = {v.x, v.y, v.z, v.w};
#pragma unroll
        for (int j = 0; j < 4; j++) {
            float f = arr[j];
            s += f * f;
            int e = i * 4 + j;
            unsigned short h = f2bf(f);
            hv[e >> 3][e & 7] = (short)h;
            lv[e >> 3][e & 7] = (short)f2bf(f - bf2f(h));
        }
    }
    short8* oh = (short8*)(cbh + (size_t)row * 64 + part * 16);
    short8* ol = (short8*)(cbl + (size_t)row * 64 + part * 16);
    oh[0] = hv[0]; oh[1] = hv[1];
    ol[0] = lv[0]; ol[1] = lv[1];
    s += __shfl_xor(s, 1, 64);
    s += __shfl_xor(s, 2, 64);
    if (part == 0) cn[row] = s;
}

#define MFMA __builtin_amdgcn_mfma_f32_16x16x32_bf16

// ---------------- fused conv_in + MFMA argmin + gather + ssd + gn-stats ----------------
// 512 blocks (= b*64+h) x 256 thr (4 waves). Block owns 64 queries (w=0..63 of
// one (b,h) row). No LDS staging of codebook: each wave reads its own disjoint
// 1024-code quarter directly from L2 (zero intra-block reuse -> staging useless).
__global__ __launch_bounds__(256, 2) void k_argmin(
    const float* __restrict__ x, const float* __restrict__ ciw, const float* __restrict__ cib,
    const unsigned short* __restrict__ cbh, const unsigned short* __restrict__ cbl,
    const float* __restrict__ cn, const float* __restrict__ cb,
    float* __restrict__ quant, float* __restrict__ ssd,
    float* __restrict__ gsum, float* __restrict__ gsq,
    unsigned int* __restrict__ rcnt, int* __restrict__ rlist) {

    __shared__ float    slab[3][3][66];
    __shared__ unsigned qtile[64][65];
    __shared__ float    mb1[4][64];
    __shared__ float    mb2[4][64];
    __shared__ int      mi1[4][64];
    __shared__ int      fi[64];
    __shared__ float    gred[4][16];

    const int tid = threadIdx.x;
    const int L   = tid & 63;
    const int wv  = tid >> 6;
    const int blk = blockIdx.x;
    const int b   = blk >> 6, h = blk & 63;

    // ---- stage x slab (zero halo) ----
    for (int idx = tid; idx < 594; idx += 256) {
        int ci = idx / 198, rem = idx - ci * 198;
        int kh = rem / 66,  colp = rem - kh * 66;
        int hh = h + kh - 1, ww = colp - 1;
        float v = 0.f;
        if (hh >= 0 && hh < 64 && ww >= 0 && ww < 64)
            v = x[((b * 3 + ci) << 12) + (hh << 6) + ww];
        slab[ci][kh][colp] = v;
    }
    __syncthreads();

    // ---- conv_in: thread (w_=L, cg=wv) computes 16 output channels ----
    {
        const int w_  = L;
        const int cgs = __builtin_amdgcn_readfirstlane(wv);
        float xv[27];
#pragma unroll
        for (int ci = 0; ci < 3; ci++)
#pragma unroll
            for (int kh = 0; kh < 3; kh++)
#pragma unroll
                for (int kw = 0; kw < 3; kw++)
                    xv[ci * 9 + kh * 3 + kw] = slab[ci][kh][w_ + kw];
#pragma unroll
        for (int j = 0; j < 16; j++) {
            int co = cgs * 16 + j;
            float acc = cib[co];
#pragma unroll
            for (int t2 = 0; t2 < 27; t2++)
                acc = fmaf(xv[t2], ciw[co * 27 + t2], acc);
            unsigned short hbits = f2bf(acc);
            unsigned short lbits = f2bf(acc - bf2f(hbits));
            qtile[w_][co] = (unsigned)hbits | ((unsigned)lbits << 16);
        }
    }
    __syncthreads();

    // ---- build A fragments from qtile ----
    const int col = L & 15, g = L >> 4;
    short8 qh[4][2], ql[4][2];
#pragma unroll
    for (int mt = 0; mt < 4; mt++) {
        int qrow = mt * 16 + col;
#pragma unroll
        for (int kh = 0; kh < 2; kh++) {
            int d0 = (kh * 4 + g) * 8;
#pragma unroll
            for (int e = 0; e < 8; e++) {
                unsigned u = qtile[qrow][d0 + e];
                qh[mt][kh][e] = (short)(u & 0xFFFFu);
                ql[mt][kh][e] = (short)(u >> 16);
            }
        }
    }

    // ---- K loop: 64 groups of 16 codes, direct global B loads, no barriers ----
    float vb1[4][4], vb2[4][4];
    int   vi1[4][4];
#pragma unroll
    for (int mt = 0; mt < 4; mt++)
#pragma unroll
        for (int e = 0; e < 4; e++) { vb1[mt][e] = 3.4e38f; vb2[mt][e] = 3.4e38f; vi1[mt][e] = 0; }

    const int cbase0 = wv << 10;
    const unsigned short* ph = cbh + (size_t)(cbase0 + col) * 64;
    const unsigned short* pl = cbl + (size_t)(cbase0 + col) * 64;

    short8 c0h0, c0h1, c0l0, c0l1, c1h0, c1h1, c1l0, c1l1;

    auto LD = [&](int gi, short8& h0, short8& h1, short8& l0, short8& l1) {
        const short8* p0 = (const short8*)(ph + ((size_t)gi << 10));
        const short8* p1 = (const short8*)(pl + ((size_t)gi << 10));
        h0 = p0[g]; h1 = p0[4 + g]; l0 = p1[g]; l1 = p1[4 + g];
    };
    auto PROC = [&](int gi, short8& h0, short8& h1, short8& l0, short8& l1) {
        int   kvb = cbase0 + gi * 16 + col;
        float cnk = cn[kvb];
#pragma unroll
        for (int mt = 0; mt < 4; mt++) {
            f32x4 acc = {0.f, 0.f, 0.f, 0.f};
            acc = MFMA(qh[mt][0], h0, acc, 0, 0, 0);
            acc = MFMA(qh[mt][1], h1, acc, 0, 0, 0);
            acc = MFMA(qh[mt][0], l0, acc, 0, 0, 0);
            acc = MFMA(qh[mt][1], l1, acc, 0, 0, 0);
            acc = MFMA(ql[mt][0], h0, acc, 0, 0, 0);
            acc = MFMA(ql[mt][1], h1, acc, 0, 0, 0);
#pragma unroll
            for (int e = 0; e < 4; e++) {
                float s = fmaf(acc[e], -2.f, cnk);
                vb2[mt][e] = __builtin_amdgcn_fmed3f(s, vb1[mt][e], vb2[mt][e]);
                bool take = s < vb1[mt][e];
                vi1[mt][e] = take ? kvb : vi1[mt][e];
                vb1[mt][e] = take ? s : vb1[mt][e];
            }
        }
    };

    LD(0, c0h0, c0h1, c0l0, c0l1);
#pragma unroll 1
    for (int gi = 0; gi < 64; gi += 2) {
        LD(gi + 1, c1h0, c1h1, c1l0, c1l1);
        PROC(gi, c0h0, c0h1, c0l0, c0l1);
        int gn = gi + 2 <= 63 ? gi + 2 : 63;
        LD(gn, c0h0, c0h1, c0l0, c0l1);
        PROC(gi + 1, c1h0, c1h1, c1l0, c1l1);
    }

    // ---- cross-lane (col) top-2 merge, then cross-wave ----
#pragma unroll
    for (int mt = 0; mt < 4; mt++)
#pragma unroll
    for (int e = 0; e < 4; e++) {
        float b1 = vb1[mt][e], b2 = vb2[mt][e];
        int i1 = vi1[mt][e];
#pragma unroll
        for (int m = 1; m < 16; m <<= 1) {
            float ob1 = __shfl_xor(b1, m, 64);
            float ob2 = __shfl_xor(b2, m, 64);
            int   oi1 = __shfl_xor(i1, m, 64);
            float hi = fmaxf(b1, ob1);
            b2 = fminf(fminf(b2, ob2), hi);
            bool take = (ob1 < b1) || ((ob1 == b1) && (oi1 < i1));
            if (take) { b1 = ob1; i1 = oi1; }
        }
        if (col == 0) {
            int qloc = mt * 16 + g * 4 + e;
            mb1[wv][qloc] = b1; mb2[wv][qloc] = b2; mi1[wv][qloc] = i1;
        }
    }
    __syncthreads();

    if (tid < 64) {
        float b1 = mb1[0][tid], b2 = mb2[0][tid];
        int i1 = mi1[0][tid];
#pragma unroll
        for (int w2 = 1; w2 < 4; w2++) {
            float ob1 = mb1[w2][tid], ob2 = mb2[w2][tid];
            int   oi1 = mi1[w2][tid];
            float hi = fmaxf(b1, ob1);
            b2 = fminf(fminf(b2, ob2), hi);
            bool take = (ob1 < b1) || ((ob1 == b1) && (oi1 < i1));
            if (take) { b1 = ob1; i1 = oi1; }
        }
        fi[tid] = i1;
        if (b2 - b1 < TAU) {
            unsigned pos = atomicAdd(rcnt, 1u);
            if (pos < RESCUE_CAP) {
                rlist[2 * pos] = blk * 64 + tid;
                rlist[2 * pos + 1] = i1;
            }
        }
    }
    __syncthreads();

    // ---- gather + quant write (NCHW) + ssd + GN partial stats ----
    {
        int qloc = tid >> 2, part = tid & 3;
        int idx = fi[qloc];
        int q = blk * 64 + qloc;
        int hw = q & 4095;
        const float* crow = cb + (size_t)idx * 64 + part * 16;
        float* qout = quant + ((size_t)b << 18) + ((size_t)(part * 16) << 12) + hw;
        float ps = 0.f, sA = 0.f, sA2 = 0.f, sB = 0.f, sB2 = 0.f;
#pragma unroll
        for (int cc = 0; cc < 16; cc++) {
            unsigned u = qtile[qloc][part * 16 + cc];
            float fv = bf2f((unsigned short)(u & 0xFFFFu)) + bf2f((unsigned short)(u >> 16));
            float cv = crow[cc];
            float d = cv - fv;
            ps += d * d;
            if (cc < 8) { sA += cv; sA2 += cv * cv; } else { sB += cv; sB2 += cv * cv; }
            qout[(size_t)cc << 12] = cv;
        }
#pragma unroll
        for (int off = 32; off; off >>= 1) ps += __shfl_down(ps, off, 64);
        if (L == 0) atomicAdd(ssd, ps);
#pragma unroll
        for (int m = 4; m <= 32; m <<= 1) {
            sA  += __shfl_xor(sA, m, 64);  sA2 += __shfl_xor(sA2, m, 64);
            sB  += __shfl_xor(sB, m, 64);  sB2 += __shfl_xor(sB2, m, 64);
        }
        if (L < 4) {
            gred[wv][L * 4 + 0] = sA;  gred[wv][L * 4 + 1] = sA2;
            gred[wv][L * 4 + 2] = sB;  gred[wv][L * 4 + 3] = sB2;
        }
    }
    __syncthreads();
    if (tid < 16) {
        float v = gred[0][tid] + gred[1][tid] + gred[2][tid] + gred[3][tid];
        int part = tid >> 2, stat = tid & 3;
        int grp = b * 8 + part * 2 + (stat >> 1);
        atomicAdd((stat & 1) ? &gsq[grp] : &gsum[grp], v);
    }
}

// ---------------- exact fp32 rescue for near-tie queries ----------------
__global__ void k_rescue(const int* __restrict__ rlist, const unsigned int* __restrict__ rcnt,
                         const float* __restrict__ x, const float* __restrict__ ciw,
                         const float* __restrict__ cib,
                         const float* __restrict__ cb, const float* __restrict__ cn,
                         float* __restrict__ quant, float* __restrict__ ssd,
                         float* __restrict__ gsum, float* __restrict__ gsq) {
    __shared__ float fqs[64];
    __shared__ float rb[4];
    __shared__ int   ri[4];
    __shared__ int   s_new;
    int tid = threadIdx.x;
    unsigned cnt = *rcnt;
    int n = (int)(cnt > RESCUE_CAP ? RESCUE_CAP : cnt);
    for (int r = blockIdx.x; r < n; r += gridDim.x) {
        int q = rlist[2 * r], old_i = rlist[2 * r + 1];
        int b = q >> 12, h = (q >> 6) & 63, w_ = q & 63;
        if (tid < 64) {                   // recompute query via conv
            float acc = cib[tid];
#pragma unroll
            for (int ci = 0; ci < 3; ci++)
#pragma unroll
            for (int kh = 0; kh < 3; kh++) {
                int hh = h + kh - 1;
                if (hh < 0 || hh >= 64) continue;
#pragma unroll
                for (int kw = 0; kw < 3; kw++) {
                    int ww = w_ + kw - 1;
                    if (ww < 0 || ww >= 64) continue;
                    acc = fmaf(x[((b * 3 + ci) << 12) + (hh << 6) + ww],
                               ciw[tid * 27 + ci * 9 + kh * 3 + kw], acc);
                }
            }
            fqs[tid] = acc;
        }
        __syncthreads();
        float best = 3.4e38f; int bi = 0;
        for (int kk = 0; kk < 16; kk++) {
            int k = kk * 256 + tid;
            const float4* cp = (const float4*)(cb + (size_t)k * 64);
            float d0 = 0.f, d1 = 0.f, d2 = 0.f, d3 = 0.f;
#pragma unroll
            for (int i = 0; i < 16; i += 4) {
                float4 c0 = cp[i], c1 = cp[i+1], c2 = cp[i+2], c3 = cp[i+3];
                d0 += fqs[4*i+ 0]*c0.x + fqs[4*i+ 1]*c0.y + fqs[4*i+ 2]*c0.z + fqs[4*i+ 3]*c0.w;
                d1 += fqs[4*i+ 4]*c1.x + fqs[4*i+ 5]*c1.y + fqs[4*i+ 6]*c1.z + fqs[4*i+ 7]*c1.w;
                d2 += fqs[4*i+ 8]*c2.x + fqs[4*i+ 9]*c2.y + fqs[4*i+10]*c2.z + fqs[4*i+11]*c2.w;
                d3 += fqs[4*i+12]*c3.x + fqs[4*i+13]*c3.y + fqs[4*i+14]*c3.z + fqs[4*i+15]*c3.w;
            }
            float s = cn[k] - 2.f * ((d0 + d1) + (d2 + d3));
            if (s < best) { best = s; bi = k; }
        }
#pragma unroll
        for (int off = 32; off; off >>= 1) {
            float ob = __shfl_down(best, off, 64);
            int   oi = __shfl_down(bi, off, 64);
            if (ob < best || (ob == best && oi < bi)) { best = ob; bi = oi; }
        }
        if ((tid & 63) == 0) { rb[tid >> 6] = best; ri[tid >> 6] = bi; }
        __syncthreads();
        if (tid == 0) {
            float bb = rb[0]; int ii = ri[0];
#pragma unroll
            for (int w2 = 1; w2 < 4; w2++)
                if (rb[w2] < bb || (rb[w2] == bb && ri[w2] < ii)) { bb = rb[w2]; ii = ri[w2]; }
            s_new = ii;
        }
        __syncthreads();
        int ni = s_new;
        if (ni != old_i && tid < 64) {
            float fv = fqs[tid];
            float co_ = cb[(size_t)old_i * 64 + tid];
            float cw  = cb[(size_t)ni * 64 + tid];
            quant[((size_t)b << 18) + ((size_t)tid << 12) + (q & 4095)] = cw;
            float dssd = (cw - fv) * (cw - fv) - (co_ - fv) * (co_ - fv);
            float ds  = cw - co_;
            float ds2 = cw * cw - co_ * co_;
#pragma unroll
            for (int off = 32; off; off >>= 1) dssd += __shfl_down(dssd, off, 64);
#pragma unroll
            for (int m = 1; m < 8; m <<= 1) {
                ds  += __shfl_xor(ds, m, 64);
                ds2 += __shfl_xor(ds2, m, 64);
            }
            if (tid == 0) atomicAdd(ssd, dssd);
            if ((tid & 7) == 0) {
                atomicAdd(&gsum[b * 8 + (tid >> 3)], ds);
                atomicAdd(&gsq [b * 8 + (tid >> 3)], ds2);
            }
        }
        __syncthreads();
    }
}

// ---------------- group-norm apply + SiLU ----------------
__global__ void k_norm_silu(const float* __restrict__ quant,
                            const float* __restrict__ gsum, const float* __restrict__ gsq,
                            const float* __restrict__ scale, const float* __restrict__ bias,
                            float* __restrict__ normed) {
    int t = blockIdx.x * 256 + threadIdx.x;
    int c = (t >> 10) & 63;
    int b = t >> 16;
    int grp = b * 8 + (c >> 3);
    float m = gsum[grp] * (1.f / 32768.f);
    float var = gsq[grp] * (1.f / 32768.f) - m * m;
    float r = rsqrtf(var + 1e-5f);
    float sc = scale[c] * r;
    float bi = bias[c] - m * sc;
    float4 v = ((const float4*)quant)[t];
    float4 o;
    float y;
    y = v.x * sc + bi; o.x = y / (1.f + expf(-y));
    y = v.y * sc + bi; o.y = y / (1.f + expf(-y));
    y = v.z * sc + bi; o.z = y / (1.f + expf(-y));
    y = v.w * sc + bi; o.w = y / (1.f + expf(-y));
    ((float4*)normed)[t] = o;
}

// ---------------- conv_out: 1536 blocks, 4-way ci split + shfl reduce ----------------
__global__ void k_conv_out(const float* __restrict__ normed, const float* __restrict__ w,
                           const float* __restrict__ bias, float* __restrict__ out) {
    int blk = blockIdx.x;                 // ((b*3+co)<<6) + h
    int h = blk & 63;
    int t2 = blk >> 6;
    int co = t2 % 3, b = t2 / 3;
    int tid = threadIdx.x;
    int ciq = tid & 3, w_ = tid >> 2;     // w_ 0..63
    float acc = 0.f;
    const float* wt = w + (size_t)(co * 64 + ciq * 16) * 9;
    const float* np = normed + ((size_t)(b * 64 + ciq * 16) << 12);
#pragma unroll 4
    for (int cj = 0; cj < 16; cj++) {
#pragma unroll
        for (int kh = 0; kh < 3; kh++) {
            int hh = h + kh - 1;
            if (hh < 0 || hh >= 64) continue;
            const float* row = np + ((size_t)cj << 12) + (hh << 6);
            float wk0 = wt[cj * 9 + kh * 3 + 0];
            float wk1 = wt[cj * 9 + kh * 3 + 1];
            float wk2 = wt[cj * 9 + kh * 3 + 2];
            if (w_ > 0)  acc = fmaf(row[w_ - 1], wk0, acc);
            acc = fmaf(row[w_], wk1, acc);
            if (w_ < 63) acc = fmaf(row[w_ + 1], wk2, acc);
        }
    }
    acc += __shfl_xor(acc, 1, 64);
    acc += __shfl_xor(acc, 2, 64);
    if (ciq == 0)
        out[((size_t)(b * 3 + co) << 12) + (h << 6) + w_] = acc + bias[co];
}

// ---------------- losses ----------------
__global__ void k_loss(const float* __restrict__ ssd, float* __restrict__ losses) {
    float mean = ssd[0] / 2097152.f;
    losses[0] = mean;
    losses[1] = 0.25f * mean;
}

extern "C" void kernel_launch(void* const* d_in, const int* in_sizes, int n_in,
                              void* d_out, int out_size, void* d_ws, size_t ws_size,
                              hipStream_t stream) {
    const float* x   = (const float*)d_in[0];
    const float* ciw = (const float*)d_in[1];
    const float* cib = (const float*)d_in[2];
    const float* cb  = (const float*)d_in[3];
    const float* gsc = (const float*)d_in[4];
    const float* gbi = (const float*)d_in[5];
    const float* dw  = (const float*)d_in[6];
    const float* db  = (const float*)d_in[7];

    float* out = (float*)d_out;
    char* wsb  = (char*)d_ws;

    float*          ssd   = (float*)wsb;                       // 4B
    unsigned int*   rcnt  = (unsigned int*)(wsb + 4);          // 4B
    float*          gsum  = (float*)(wsb + 64);                // 256B
    float*          gsq   = (float*)(wsb + 320);               // 256B
    float*          cn    = (float*)(wsb + 1024);              // 16KB
    int*            rlist = (int*)(wsb + 65536);               // 64KB
    unsigned short* cbh   = (unsigned short*)(wsb + 131072);   // 512KB
    unsigned short* cbl   = (unsigned short*)(wsb + 655360);   // 512KB
    float*          normed = (float*)(wsb + 1179648);          // 8MB

    float* recon  = out;                    // 98304
    float* quant  = out + 98304;            // 2097152
    float* losses = out + 98304 + NELEM;    // 2

    hipMemsetAsync(wsb, 0, 1024, stream);
    k_prep     <<<64,   256, 0, stream>>>(cb, cn, cbh, cbl);
    k_argmin   <<<512,  256, 0, stream>>>(x, ciw, cib, cbh, cbl, cn, cb,
                                          quant, ssd, gsum, gsq, rcnt, rlist);
    k_rescue   <<<128,  256, 0, stream>>>(rlist, rcnt, x, ciw, cib, cb, cn,
                                          quant, ssd, gsum, gsq);
    k_norm_silu<<<2048, 256, 0, stream>>>(quant, gsum, gsq, gsc, gbi, normed);
    k_conv_out <<<1536, 256, 0, stream>>>(normed, dw, db, recon);
    k_loss     <<<1,    1,   0, stream>>>(ssd, losses);
}